// Round 1
// baseline (484.343 us; speedup 1.0000x reference)
//
#include <hip/hip_runtime.h>
#include <math.h>

#define CB_K 256
#define PQ_D 8

// ---------------- PQ quantization (fp32-exact argmin) ----------------
// w: [O, I] row-major; groups of PQ_D along I. rs: [O]. out: [O, I].
__global__ __launch_bounds__(256)
void pq_quant(const float* __restrict__ w,
              const float* __restrict__ cb,
              const float* __restrict__ rs,
              float* __restrict__ out,
              int n_groups, int groups_per_row)
{
    __shared__ float s_cb[CB_K * PQ_D];
    __shared__ float s_cb2[CB_K];
    const int tid = threadIdx.x;
    for (int i = tid; i < CB_K * PQ_D; i += 256) s_cb[i] = cb[i];
    __syncthreads();
    if (tid < CB_K) {
        float s = 0.f;
#pragma unroll
        for (int j = 0; j < PQ_D; j++) { float c = s_cb[tid * PQ_D + j]; s += c * c; }
        s_cb2[tid] = s;
    }
    __syncthreads();

    const int g = blockIdx.x * 256 + tid;
    if (g >= n_groups) return;
    const int row = g / groups_per_row;
    const float scale = rs[row];

    const float4* wp = (const float4*)(w + (size_t)g * PQ_D);
    float4 w0 = wp[0], w1 = wp[1];
    float x[PQ_D] = {w0.x, w0.y, w0.z, w0.w, w1.x, w1.y, w1.z, w1.w};
#pragma unroll
    for (int j = 0; j < PQ_D; j++) x[j] = x[j] / scale;   // match reference: w / row_scale
    float x2 = 0.f;
#pragma unroll
    for (int j = 0; j < PQ_D; j++) x2 += x[j] * x[j];

    const float4* scb4 = (const float4*)s_cb;
    float best = INFINITY;
    int bi = 0;
    for (int k = 0; k < CB_K; k++) {
        float4 c0 = scb4[k * 2 + 0];
        float4 c1 = scb4[k * 2 + 1];
        float dot = x[0] * c0.x + x[1] * c0.y + x[2] * c0.z + x[3] * c0.w
                  + x[4] * c1.x + x[5] * c1.y + x[6] * c1.z + x[7] * c1.w;
        float d2 = x2 - 2.0f * dot + s_cb2[k];
        if (d2 < best) { best = d2; bi = k; }   // strict <  == first-occurrence argmin
    }

    float4 o0, o1;
    o0.x = s_cb[bi * PQ_D + 0] * scale;
    o0.y = s_cb[bi * PQ_D + 1] * scale;
    o0.z = s_cb[bi * PQ_D + 2] * scale;
    o0.w = s_cb[bi * PQ_D + 3] * scale;
    o1.x = s_cb[bi * PQ_D + 4] * scale;
    o1.y = s_cb[bi * PQ_D + 5] * scale;
    o1.z = s_cb[bi * PQ_D + 6] * scale;
    o1.w = s_cb[bi * PQ_D + 7] * scale;
    float4* op = (float4*)(out + (size_t)g * PQ_D);
    op[0] = o0;
    op[1] = o1;
}

// ---------------- fp32 SGEMM: C[M,N] = A[M,K] * B[K,N] ----------------
// 128x128 block tile, BK=16, 256 threads, 8x8 per thread (4+4 split layout).
#define BM 128
#define BN 128
#define BK 16

__global__ __launch_bounds__(256)
void sgemm128(const float* __restrict__ A, const float* __restrict__ B,
              float* __restrict__ C, int M, int N, int K)
{
    __shared__ float sA[BK][BM + 4];   // +4 pad: transposed scalar stores -> 2-way (free)
    __shared__ float sB[BK][BN];

    const int tid = threadIdx.x;
    const int tx = tid & 15;    // n-dir
    const int ty = tid >> 4;    // m-dir
    const int bm = blockIdx.y * BM;
    const int bn = blockIdx.x * BN;

    float acc[8][8];
#pragma unroll
    for (int i = 0; i < 8; i++)
#pragma unroll
        for (int j = 0; j < 8; j++) acc[i][j] = 0.f;

    // A-tile: 128 rows x 16 k. thread -> rows (tid>>2), (tid>>2)+64 ; 4 floats at col (tid&3)*4
    const int arow = tid >> 2;
    const int acol = (tid & 3) * 4;
    // B-tile: 16 k x 128 cols. thread -> k rows (tid>>5), (tid>>5)+8 ; 4 floats at col (tid&31)*4
    const int brow = tid >> 5;
    const int bcol = (tid & 31) * 4;

    for (int k0 = 0; k0 < K; k0 += BK) {
        float4 a0 = *(const float4*)(A + (size_t)(bm + arow)      * K + k0 + acol);
        float4 a1 = *(const float4*)(A + (size_t)(bm + arow + 64) * K + k0 + acol);
        float4 b0 = *(const float4*)(B + (size_t)(k0 + brow)     * N + bn + bcol);
        float4 b1 = *(const float4*)(B + (size_t)(k0 + brow + 8) * N + bn + bcol);

        __syncthreads();   // previous iteration's LDS reads done before overwrite
        sA[acol + 0][arow] = a0.x; sA[acol + 1][arow] = a0.y;
        sA[acol + 2][arow] = a0.z; sA[acol + 3][arow] = a0.w;
        sA[acol + 0][arow + 64] = a1.x; sA[acol + 1][arow + 64] = a1.y;
        sA[acol + 2][arow + 64] = a1.z; sA[acol + 3][arow + 64] = a1.w;
        *(float4*)&sB[brow][bcol]     = b0;
        *(float4*)&sB[brow + 8][bcol] = b1;
        __syncthreads();

#pragma unroll
        for (int k = 0; k < BK; k++) {
            float4 a0v = *(const float4*)&sA[k][ty * 4];
            float4 a1v = *(const float4*)&sA[k][ty * 4 + 64];
            float4 b0v = *(const float4*)&sB[k][tx * 4];
            float4 b1v = *(const float4*)&sB[k][tx * 4 + 64];
            float av[8] = {a0v.x, a0v.y, a0v.z, a0v.w, a1v.x, a1v.y, a1v.z, a1v.w};
            float bv[8] = {b0v.x, b0v.y, b0v.z, b0v.w, b1v.x, b1v.y, b1v.z, b1v.w};
#pragma unroll
            for (int i = 0; i < 8; i++)
#pragma unroll
                for (int j = 0; j < 8; j++) acc[i][j] += av[i] * bv[j];
        }
    }

    // C write: rows bm + ty*4 + {0..3} and +64; cols bn + tx*4 + {0..3} and +64
#pragma unroll
    for (int i = 0; i < 8; i++) {
        const int r = bm + ty * 4 + ((i < 4) ? i : (64 + i - 4));
        float4 v0 = make_float4(acc[i][0], acc[i][1], acc[i][2], acc[i][3]);
        float4 v1 = make_float4(acc[i][4], acc[i][5], acc[i][6], acc[i][7]);
        *(float4*)(C + (size_t)r * N + bn + tx * 4)      = v0;
        *(float4*)(C + (size_t)r * N + bn + tx * 4 + 64) = v1;
    }
}

// ---------------- launch ----------------
extern "C" void kernel_launch(void* const* d_in, const int* in_sizes, int n_in,
                              void* d_out, int out_size, void* d_ws, size_t ws_size,
                              hipStream_t stream)
{
    const float* U    = (const float*)d_in[0];   // [32768, 256]
    const float* B    = (const float*)d_in[1];   // [256, 1024]
    const float* rs_U = (const float*)d_in[2];   // [32768]
    const float* rs_B = (const float*)d_in[3];   // [256]
    const float* cb_U = (const float*)d_in[4];   // [256, 8]
    const float* cb_B = (const float*)d_in[5];   // [256, 8]
    float* out = (float*)d_out;                  // [32768, 1024]

    const int Krows = 32768, r = 256, d = 1024;

    float* Uq = (float*)d_ws;                    // 32 MB
    float* Bq = Uq + (size_t)Krows * r;          // 1 MB

    const int ngU = Krows * r / PQ_D;            // 1,048,576 groups
    pq_quant<<<ngU / 256, 256, 0, stream>>>(U, cb_U, rs_U, Uq, ngU, r / PQ_D);

    const int ngB = r * d / PQ_D;                // 32,768 groups
    pq_quant<<<ngB / 256, 256, 0, stream>>>(B, cb_B, rs_B, Bq, ngB, d / PQ_D);

    dim3 grid(d / BN, Krows / BM);               // (8, 256)
    sgemm128<<<grid, 256, 0, stream>>>(Uq, Bq, out, Krows, d, r);
}

// Round 2
// 299.830 us; speedup vs baseline: 1.6154x; 1.6154x over previous
//
#include <hip/hip_runtime.h>
#include <math.h>

#define CB_K 256
#define PQ_D 8

typedef __attribute__((ext_vector_type(2))) float f32x2;
typedef __attribute__((ext_vector_type(4))) float f32x4;
typedef __attribute__((ext_vector_type(8))) short bf16x8;

__device__ __forceinline__ ushort f2bf(float f) {
    unsigned u = __float_as_uint(f);
    unsigned r = (u + 0x7FFFu + ((u >> 16) & 1u)) >> 16;   // RNE
    return (ushort)r;
}
__device__ __forceinline__ float bf2f(ushort h) {
    return __uint_as_float(((unsigned)h) << 16);
}

// ============ PQ quantize + split into bf16 hi/lo, row-major out ============
// argmin_k |w/s - c_k|^2  ==  argmin_k [ s*|c_k|^2 - 2 w.c_k ]   (s > 0)
template <int LOG2_GPR>
__global__ __launch_bounds__(256)
void pq_quant_split(const float* __restrict__ w, const float* __restrict__ cb,
                    const float* __restrict__ rs,
                    ushort* __restrict__ oh, ushort* __restrict__ ol)
{
    __shared__ float s_cb[CB_K * PQ_D];
    __shared__ float s_cb2[CB_K];
    const int t = threadIdx.x;
    for (int i = t; i < CB_K * PQ_D; i += 256) s_cb[i] = cb[i];
    __syncthreads();
    {
        float s = 0.f;
#pragma unroll
        for (int j = 0; j < PQ_D; j++) { float c = s_cb[t * PQ_D + j]; s += c * c; }
        s_cb2[t] = s;
    }
    __syncthreads();

    const int gbase = blockIdx.x * 1024;          // 4 groups per thread, strided
    f32x2 xm2[4][4];
    float sc[4], best[4];
    int   bi[4];
#pragma unroll
    for (int j = 0; j < 4; j++) {
        const int g = gbase + j * 256 + t;
        sc[j] = rs[g >> LOG2_GPR];
        const float4* wp = (const float4*)(w + (size_t)g * PQ_D);
        float4 a = wp[0], b = wp[1];
        xm2[j][0] = f32x2{-2.f * a.x, -2.f * a.y};
        xm2[j][1] = f32x2{-2.f * a.z, -2.f * a.w};
        xm2[j][2] = f32x2{-2.f * b.x, -2.f * b.y};
        xm2[j][3] = f32x2{-2.f * b.z, -2.f * b.w};
        best[j] = INFINITY; bi[j] = 0;
    }

    for (int k = 0; k < CB_K; k++) {
        const float4 c01 = *(const float4*)(s_cb + k * PQ_D);
        const float4 c23 = *(const float4*)(s_cb + k * PQ_D + 4);
        const float  cc  = s_cb2[k];
        const f32x2 c0{c01.x, c01.y}, c1{c01.z, c01.w}, c2{c23.x, c23.y}, c3{c23.z, c23.w};
#pragma unroll
        for (int j = 0; j < 4; j++) {
            f32x2 acc = xm2[j][0] * c0;
            acc += xm2[j][1] * c1;
            acc += xm2[j][2] * c2;
            acc += xm2[j][3] * c3;
            float val = fmaf(sc[j], cc, acc.x + acc.y);
            bool p = val < best[j];               // strict <: first-occurrence argmin
            best[j] = p ? val : best[j];
            bi[j]   = p ? k : bi[j];
        }
    }

#pragma unroll
    for (int j = 0; j < 4; j++) {
        const int g = gbase + j * 256 + t;
        const float4* cp = (const float4*)(s_cb + bi[j] * PQ_D);
        float4 q0 = cp[0], q1 = cp[1];
        float v[8] = {q0.x, q0.y, q0.z, q0.w, q1.x, q1.y, q1.z, q1.w};
        bf16x8 vh, vl;
#pragma unroll
        for (int e = 0; e < 8; e++) {
            float f = v[e] * sc[j];               // same op as reference epilogue
            ushort h = f2bf(f);
            vh[e] = (short)h;
            vl[e] = (short)f2bf(f - bf2f(h));
        }
        *(bf16x8*)(oh + (size_t)g * PQ_D) = vh;
        *(bf16x8*)(ol + (size_t)g * PQ_D) = vl;
    }
}

// ============ PQ quantize B + split + TRANSPOSED store: out[I][O] ============
__global__ __launch_bounds__(256)
void pq_quant_split_T(const float* __restrict__ w, const float* __restrict__ cb,
                      const float* __restrict__ rs,
                      ushort* __restrict__ oh, ushort* __restrict__ ol,
                      int log2_gpr, int O)
{
    __shared__ float s_cb[CB_K * PQ_D];
    __shared__ float s_cb2[CB_K];
    const int t = threadIdx.x;
    for (int i = t; i < CB_K * PQ_D; i += 256) s_cb[i] = cb[i];
    __syncthreads();
    {
        float s = 0.f;
#pragma unroll
        for (int j = 0; j < PQ_D; j++) { float c = s_cb[t * PQ_D + j]; s += c * c; }
        s_cb2[t] = s;
    }
    __syncthreads();

    const int g = blockIdx.x * 256 + t;
    const int gpr_mask = (1 << log2_gpr) - 1;
    const int row  = g >> log2_gpr;               // source row (k of the GEMM)
    const int col0 = (g & gpr_mask) * PQ_D;       // source col (n of the GEMM)
    const float s = rs[row];

    const float4* wp = (const float4*)(w + (size_t)g * PQ_D);
    float4 a = wp[0], b = wp[1];
    f32x2 xm2[4] = {f32x2{-2.f * a.x, -2.f * a.y}, f32x2{-2.f * a.z, -2.f * a.w},
                    f32x2{-2.f * b.x, -2.f * b.y}, f32x2{-2.f * b.z, -2.f * b.w}};
    float best = INFINITY; int bi = 0;
    for (int k = 0; k < CB_K; k++) {
        const float4 c01 = *(const float4*)(s_cb + k * PQ_D);
        const float4 c23 = *(const float4*)(s_cb + k * PQ_D + 4);
        f32x2 acc = xm2[0] * f32x2{c01.x, c01.y};
        acc += xm2[1] * f32x2{c01.z, c01.w};
        acc += xm2[2] * f32x2{c23.x, c23.y};
        acc += xm2[3] * f32x2{c23.z, c23.w};
        float val = fmaf(s, s_cb2[k], acc.x + acc.y);
        bool p = val < best;
        best = p ? val : best;
        bi   = p ? k : bi;
    }

    const float4* cp = (const float4*)(s_cb + bi * PQ_D);
    float4 q0 = cp[0], q1 = cp[1];
    float v[8] = {q0.x, q0.y, q0.z, q0.w, q1.x, q1.y, q1.z, q1.w};
#pragma unroll
    for (int e = 0; e < 8; e++) {
        float f = v[e] * s;
        ushort h = f2bf(f);
        oh[(size_t)(col0 + e) * O + row] = h;
        ol[(size_t)(col0 + e) * O + row] = f2bf(f - bf2f(h));
    }
}

// ============ 3-term split-bf16 MFMA GEMM: C = Ah*Bh + Ah*Bl + Al*Bh ============
// A* : [M][K] bf16 row-major.  B* : [N][K] bf16 row-major (= B^T).  C: [M][N] f32.
#define BM 128
#define BN 128
#define BK 64

__device__ __forceinline__ void gl_lds16(const void* g, void* l) {
    __builtin_amdgcn_global_load_lds((const __attribute__((address_space(1))) void*)g,
                                     (__attribute__((address_space(3))) void*)l, 16, 0, 0);
}

__global__ __launch_bounds__(256, 2)
void gemm3(const ushort* __restrict__ Ah, const ushort* __restrict__ Al,
           const ushort* __restrict__ Bh, const ushort* __restrict__ Bl,
           float* __restrict__ C, int M, int N, int K)
{
    // [128 rows][64 k] bf16 = 128B/row; XOR-swizzle: byte ^= ((row&7)<<4)
    __shared__ __align__(16) ushort sAh[BM * BK], sAl[BM * BK];
    __shared__ __align__(16) ushort sBh[BN * BK], sBl[BN * BK];

    const int t    = threadIdx.x;
    const int lane = t & 63;
    const int wv   = t >> 6;
    const int wr = wv >> 1, wc = wv & 1;
    const int l15 = lane & 15, kq = lane >> 4;
    const int bm = blockIdx.y * BM, bn = blockIdx.x * BN;

    // staging geometry: round r covers linear bytes [r*4096, r*4096+4096)
    int srow[4], sslot[4];
#pragma unroll
    for (int r = 0; r < 4; r++) {
        int n = r * 4096 + t * 16;
        int row = n >> 7;
        int slot = ((n >> 4) & 7) ^ (row & 7);    // inverse-swizzled source slot
        srow[r] = row; sslot[r] = slot;
    }

    f32x4 acc[4][4];
#pragma unroll
    for (int i = 0; i < 4; i++)
#pragma unroll
        for (int j = 0; j < 4; j++) acc[i][j] = f32x4{0.f, 0.f, 0.f, 0.f};

    const char* pAh = (const char*)Ah;
    const char* pAl = (const char*)Al;
    const char* pBh = (const char*)Bh;
    const char* pBl = (const char*)Bl;

    for (int ks = 0; ks < K / BK; ks++) {
        const int k0 = ks * BK;
        if (ks) __syncthreads();
#pragma unroll
        for (int r = 0; r < 4; r++) {
            size_t offA = ((size_t)(bm + srow[r]) * K + k0 + sslot[r] * 8) * 2;
            size_t offB = ((size_t)(bn + srow[r]) * K + k0 + sslot[r] * 8) * 2;
            int ldso = r * 4096 + wv * 1024;      // wave-uniform dest; HW adds lane*16
            gl_lds16(pAh + offA, (char*)sAh + ldso);
            gl_lds16(pAl + offA, (char*)sAl + ldso);
            gl_lds16(pBh + offB, (char*)sBh + ldso);
            gl_lds16(pBl + offB, (char*)sBl + ldso);
        }
        __syncthreads();

#pragma unroll
        for (int kk = 0; kk < 2; kk++) {
            bf16x8 ah[4], al[4], bh[4], bl[4];
#pragma unroll
            for (int f = 0; f < 4; f++) {
                int mr = wr * 64 + f * 16 + l15;
                int offa = mr * 128 + (((kk * 4 + kq) ^ (mr & 7)) * 16);
                ah[f] = *(const bf16x8*)((const char*)sAh + offa);
                al[f] = *(const bf16x8*)((const char*)sAl + offa);
                int nr = wc * 64 + f * 16 + l15;
                int offb = nr * 128 + (((kk * 4 + kq) ^ (nr & 7)) * 16);
                bh[f] = *(const bf16x8*)((const char*)sBh + offb);
                bl[f] = *(const bf16x8*)((const char*)sBl + offb);
            }
#pragma unroll
            for (int mf = 0; mf < 4; mf++)
#pragma unroll
                for (int nf = 0; nf < 4; nf++) {
                    acc[mf][nf] = __builtin_amdgcn_mfma_f32_16x16x32_bf16(ah[mf], bh[nf], acc[mf][nf], 0, 0, 0);
                    acc[mf][nf] = __builtin_amdgcn_mfma_f32_16x16x32_bf16(ah[mf], bl[nf], acc[mf][nf], 0, 0, 0);
                    acc[mf][nf] = __builtin_amdgcn_mfma_f32_16x16x32_bf16(al[mf], bh[nf], acc[mf][nf], 0, 0, 0);
                }
        }
    }

    // epilogue: C[row=(lane>>4)*4+r][col=lane&15] per 16x16 fragment (m89 layout)
#pragma unroll
    for (int mf = 0; mf < 4; mf++) {
        const int r0 = bm + wr * 64 + mf * 16 + kq * 4;
#pragma unroll
        for (int nf = 0; nf < 4; nf++) {
            const int cc = bn + wc * 64 + nf * 16 + l15;
#pragma unroll
            for (int rr = 0; rr < 4; rr++)
                C[(size_t)(r0 + rr) * N + cc] = acc[mf][nf][rr];
        }
    }
}

// ---------------- launch ----------------
extern "C" void kernel_launch(void* const* d_in, const int* in_sizes, int n_in,
                              void* d_out, int out_size, void* d_ws, size_t ws_size,
                              hipStream_t stream)
{
    const float* U    = (const float*)d_in[0];   // [32768, 256]
    const float* B    = (const float*)d_in[1];   // [256, 1024]
    const float* rs_U = (const float*)d_in[2];
    const float* rs_B = (const float*)d_in[3];
    const float* cb_U = (const float*)d_in[4];
    const float* cb_B = (const float*)d_in[5];
    float* out = (float*)d_out;                  // [32768, 1024]

    const int M = 32768, K = 256, N = 1024;

    ushort* Ahi  = (ushort*)d_ws;                // 16 MB
    ushort* Alo  = Ahi + (size_t)M * K;          // 16 MB
    ushort* BThi = Alo + (size_t)M * K;          // 512 KB
    ushort* BTlo = BThi + (size_t)N * K;         // 512 KB

    // U: groups_per_row = 256/8 = 32 = 2^5 ; 1,048,576 groups / 1024 per block
    pq_quant_split<5><<<1024, 256, 0, stream>>>(U, cb_U, rs_U, Ahi, Alo);
    // B: groups_per_row = 1024/8 = 128 = 2^7 ; 32768 groups, transposed store
    pq_quant_split_T<<<128, 256, 0, stream>>>(B, cb_B, rs_B, BThi, BTlo, 7, K);

    dim3 grid(N / BN, M / BM);                   // (8, 256), x = n (A-slice L2 reuse)
    gemm3<<<grid, 256, 0, stream>>>(Ahi, Alo, BThi, BTlo, out, M, N, K);
}

// Round 4
// 293.322 us; speedup vs baseline: 1.6512x; 1.0222x over previous
//
#include <hip/hip_runtime.h>
#include <math.h>

#define CB_K 256
#define PQ_D 8

typedef __attribute__((ext_vector_type(2))) float f32x2;
typedef __attribute__((ext_vector_type(4))) float f32x4;
typedef __attribute__((ext_vector_type(8))) short bf16x8;
typedef __attribute__((ext_vector_type(4))) unsigned int u32x4;

__device__ __forceinline__ ushort f2bf(float f) {
    unsigned u = __float_as_uint(f);
    unsigned r = (u + 0x7FFFu + ((u >> 16) & 1u)) >> 16;   // RNE
    return (ushort)r;
}
__device__ __forceinline__ float bf2f(ushort h) {
    return __uint_as_float(((unsigned)h) << 16);
}
__device__ __forceinline__ unsigned pk2(ushort lo, ushort hi) {
    return (unsigned)lo | ((unsigned)hi << 16);
}

// ================= U-quantize via MFMA distance + in-reg argmin =================
// d[g,k] = u_g . v_k ;  u = [-2w(8), s],  v = [c(8), |c|^2]   (argmin-equivalent
// to reference since s>0).  3-level bf16 split of both sides; A-row (codeword)
// k-concat: [vh0-7 | vm0-7 | vl0-7 | vh8 vm8 vl8 | pad0]; three B variants give
// uh.(vh+vm+vl) + um.(vh+vm) + ul.vh  (dropped terms ~2^-24 rel).
// B fragments need no LDS: lane (kq,l15) computes exactly its own 8 B values.
__global__ __launch_bounds__(256)
void pq_quant_mfma_u(const float* __restrict__ w, const float* __restrict__ cb,
                     const float* __restrict__ rs,
                     ushort* __restrict__ oh, ushort* __restrict__ ol)
{
    __shared__ ushort A_lds[CB_K][40];        // 20 KB; row stride 80 B (16B-aligned, bank-spread)

    const int t = threadIdx.x;

    // ---- A (codeword) table: thread t = codeword t, built once ----
    {
        const float* cp = cb + t * PQ_D;
        float v[9]; float cc = 0.f;
#pragma unroll
        for (int j = 0; j < 8; j++) { float c = cp[j]; v[j] = c; cc += c * c; }
        v[8] = cc;
        ushort hh[9], mm[9], ll[9];
#pragma unroll
        for (int j = 0; j < 9; j++) {
            float x = v[j];
            ushort h = f2bf(x); float r  = x - bf2f(h);
            ushort m = f2bf(r); float r2 = r - bf2f(m);
            hh[j] = h; mm[j] = m; ll[j] = f2bf(r2);
        }
        *(u32x4*)&A_lds[t][0]  = u32x4{pk2(hh[0],hh[1]), pk2(hh[2],hh[3]), pk2(hh[4],hh[5]), pk2(hh[6],hh[7])};
        *(u32x4*)&A_lds[t][8]  = u32x4{pk2(mm[0],mm[1]), pk2(mm[2],mm[3]), pk2(mm[4],mm[5]), pk2(mm[6],mm[7])};
        *(u32x4*)&A_lds[t][16] = u32x4{pk2(ll[0],ll[1]), pk2(ll[2],ll[3]), pk2(ll[4],ll[5]), pk2(ll[6],ll[7])};
        *(u32x4*)&A_lds[t][24] = u32x4{pk2(hh[8],mm[8]), pk2(ll[8],0), 0u, 0u};
    }
    __syncthreads();

    const int lane = t & 63;
    const int wv   = t >> 6;
    const int l15  = lane & 15;
    const int kq   = lane >> 4;          // k-slice quarter, also C row-group
    const int kq4  = kq * 4;
    const int gw   = blockIdx.x * 4 + wv;

    for (int it = 0; it < 16; it++) {
        const int tile = gw * 16 + it;
        const int g    = tile * 16 + l15;
        const float s  = rs[g >> 5];                  // 32 groups per U row

        // ---- B fragments, fully in-register (lane covers (group=l15, slice=kq)) ----
        const float4* wp = (const float4*)(w + (size_t)g * PQ_D);
        float4 wa = wp[0], wb = wp[1];
        float u[8] = {-2.f*wa.x, -2.f*wa.y, -2.f*wa.z, -2.f*wa.w,
                      -2.f*wb.x, -2.f*wb.y, -2.f*wb.z, -2.f*wb.w};
        ushort uh[8], um[8], ul[8];
#pragma unroll
        for (int j = 0; j < 8; j++) {
            ushort h = f2bf(u[j]); float r  = u[j] - bf2f(h);
            ushort m = f2bf(r);    float r2 = r - bf2f(m);
            uh[j] = h; um[j] = m; ul[j] = f2bf(r2);
        }
        ushort sh = f2bf(s); float sr = s - bf2f(sh);
        ushort sm = f2bf(sr); ushort sl = f2bf(sr - bf2f(sm));

        u32x4 Ph{pk2(uh[0],uh[1]), pk2(uh[2],uh[3]), pk2(uh[4],uh[5]), pk2(uh[6],uh[7])};
        u32x4 Pm{pk2(um[0],um[1]), pk2(um[2],um[3]), pk2(um[4],um[5]), pk2(um[6],um[7])};
        u32x4 Pl{pk2(ul[0],ul[1]), pk2(ul[2],ul[3]), pk2(ul[4],ul[5]), pk2(ul[6],ul[7])};
        u32x4 Z{0u,0u,0u,0u};
        u32x4 S1{pk2(sh,sh), pk2(sh,0), 0u, 0u};     // k=24,25,26 : sh
        u32x4 S2{pk2(sm,sm), 0u, 0u, 0u};            // k=24,25    : sm
        u32x4 S3{pk2(sl,0), 0u, 0u, 0u};             // k=24       : sl

        u32x4 w1 = (kq == 3) ? S1 : Ph;
        u32x4 w2 = (kq == 3) ? S2 : ((kq <= 1) ? Pm : Z);
        u32x4 w3 = (kq == 3) ? S3 : ((kq == 0) ? Pl : Z);

        bf16x8 b1 = __builtin_bit_cast(bf16x8, w1);
        bf16x8 b2 = __builtin_bit_cast(bf16x8, w2);
        bf16x8 b3 = __builtin_bit_cast(bf16x8, w3);

        float best = INFINITY;
        int   bidx = 0;
#pragma unroll
        for (int mt = 0; mt < 16; mt++) {
            bf16x8 a = *(const bf16x8*)&A_lds[mt * 16 + l15][kq4 * 2];
            f32x4 acc{0.f, 0.f, 0.f, 0.f};
            acc = __builtin_amdgcn_mfma_f32_16x16x32_bf16(a, b1, acc, 0, 0, 0);
            acc = __builtin_amdgcn_mfma_f32_16x16x32_bf16(a, b2, acc, 0, 0, 0);
            acc = __builtin_amdgcn_mfma_f32_16x16x32_bf16(a, b3, acc, 0, 0, 0);
#pragma unroll
            for (int r = 0; r < 4; r++) {
                int kk = mt * 16 + r + kq4;          // in-lane candidates k-ascending
                bool p = acc[r] < best;              // strict <: first occurrence
                best = p ? acc[r] : best;
                bidx = p ? kk : bidx;
            }
        }
        // reduce across the 4 kq lane-groups (tie-break: smaller k)
#pragma unroll
        for (int msk = 16; msk <= 32; msk <<= 1) {
            float ob = __shfl_xor(best, msk);
            int   oi = __shfl_xor(bidx, msk);
            bool p = (ob < best) || (ob == best && oi < bidx);
            best = p ? ob : best;
            bidx = p ? oi : bidx;
        }
        // ---- epilogue: lanes kq==0 write hi/lo bf16 rows of Uq ----
        if (kq == 0) {
            const float4* cp2 = (const float4*)(cb + bidx * PQ_D);
            float4 c0 = cp2[0], c1 = cp2[1];
            float y[8] = {c0.x*s, c0.y*s, c0.z*s, c0.w*s, c1.x*s, c1.y*s, c1.z*s, c1.w*s};
            ushort yh[8], yl[8];
#pragma unroll
            for (int j = 0; j < 8; j++) {
                ushort h = f2bf(y[j]);
                yh[j] = h; yl[j] = f2bf(y[j] - bf2f(h));
            }
            *(u32x4*)(oh + (size_t)g * PQ_D) =
                u32x4{pk2(yh[0],yh[1]), pk2(yh[2],yh[3]), pk2(yh[4],yh[5]), pk2(yh[6],yh[7])};
            *(u32x4*)(ol + (size_t)g * PQ_D) =
                u32x4{pk2(yl[0],yl[1]), pk2(yl[2],yl[3]), pk2(yl[4],yl[5]), pk2(yl[6],yl[7])};
        }
    }
}

// ============ PQ quantize B + split + TRANSPOSED store (validated R2) ============
__global__ __launch_bounds__(256)
void pq_quant_split_T(const float* __restrict__ w, const float* __restrict__ cb,
                      const float* __restrict__ rs,
                      ushort* __restrict__ oh, ushort* __restrict__ ol,
                      int log2_gpr, int O)
{
    __shared__ float s_cb[CB_K * PQ_D];
    __shared__ float s_cb2[CB_K];
    const int t = threadIdx.x;
    for (int i = t; i < CB_K * PQ_D; i += 256) s_cb[i] = cb[i];
    __syncthreads();
    {
        float s = 0.f;
#pragma unroll
        for (int j = 0; j < PQ_D; j++) { float c = s_cb[t * PQ_D + j]; s += c * c; }
        s_cb2[t] = s;
    }
    __syncthreads();

    const int g = blockIdx.x * 256 + t;
    const int gpr_mask = (1 << log2_gpr) - 1;
    const int row  = g >> log2_gpr;
    const int col0 = (g & gpr_mask) * PQ_D;
    const float s = rs[row];

    const float4* wp = (const float4*)(w + (size_t)g * PQ_D);
    float4 a = wp[0], b = wp[1];
    f32x2 xm2[4] = {f32x2{-2.f * a.x, -2.f * a.y}, f32x2{-2.f * a.z, -2.f * a.w},
                    f32x2{-2.f * b.x, -2.f * b.y}, f32x2{-2.f * b.z, -2.f * b.w}};
    float best = INFINITY; int bi = 0;
    for (int k = 0; k < CB_K; k++) {
        const float4 c01 = *(const float4*)(s_cb + k * PQ_D);
        const float4 c23 = *(const float4*)(s_cb + k * PQ_D + 4);
        f32x2 acc = xm2[0] * f32x2{c01.x, c01.y};
        acc += xm2[1] * f32x2{c01.z, c01.w};
        acc += xm2[2] * f32x2{c23.x, c23.y};
        acc += xm2[3] * f32x2{c23.z, c23.w};
        float val = fmaf(s, s_cb2[k], acc.x + acc.y);
        bool p = val < best;
        best = p ? val : best;
        bi   = p ? k : bi;
    }

    const float4* cp = (const float4*)(s_cb + bi * PQ_D);
    float4 q0 = cp[0], q1 = cp[1];
    float v[8] = {q0.x, q0.y, q0.z, q0.w, q1.x, q1.y, q1.z, q1.w};
#pragma unroll
    for (int e = 0; e < 8; e++) {
        float f = v[e] * s;
        ushort h = f2bf(f);
        oh[(size_t)(col0 + e) * O + row] = h;
        ol[(size_t)(col0 + e) * O + row] = f2bf(f - bf2f(h));
    }
}

// ============ 3-term split-bf16 MFMA GEMM (validated R2) + XCD remap ============
#define BM 128
#define BN 128
#define BK 64

__device__ __forceinline__ void gl_lds16(const void* g, void* l) {
    __builtin_amdgcn_global_load_lds((const __attribute__((address_space(1))) void*)g,
                                     (__attribute__((address_space(3))) void*)l, 16, 0, 0);
}

__global__ __launch_bounds__(256, 2)
void gemm3(const ushort* __restrict__ Ah, const ushort* __restrict__ Al,
           const ushort* __restrict__ Bh, const ushort* __restrict__ Bl,
           float* __restrict__ C, int M, int N, int K)
{
    __shared__ __align__(16) ushort sAh[BM * BK], sAl[BM * BK];
    __shared__ __align__(16) ushort sBh[BN * BK], sBl[BN * BK];

    const int t    = threadIdx.x;
    const int lane = t & 63;
    const int wv   = t >> 6;
    const int wr = wv >> 1, wc = wv & 1;
    const int l15 = lane & 15, kq = lane >> 4;

    // XCD remap: each XCD (id%8) walks the 8 bn-tiles of one bm-panel consecutively.
    const int h   = blockIdx.x;            // 0..2047
    const int xcd = h & 7;
    const int tt  = h >> 3;
    const int bn_i = tt & 7, bm8 = tt >> 3;
    const int bm = (bm8 * 8 + xcd) * BM;
    const int bn = bn_i * BN;

    int srow[4], sslot[4];
#pragma unroll
    for (int r = 0; r < 4; r++) {
        int n = r * 4096 + t * 16;
        int row = n >> 7;
        int slot = ((n >> 4) & 7) ^ (row & 7);    // inverse-swizzled source slot
        srow[r] = row; sslot[r] = slot;
    }

    f32x4 acc[4][4];
#pragma unroll
    for (int i = 0; i < 4; i++)
#pragma unroll
        for (int j = 0; j < 4; j++) acc[i][j] = f32x4{0.f, 0.f, 0.f, 0.f};

    const char* pAh = (const char*)Ah;
    const char* pAl = (const char*)Al;
    const char* pBh = (const char*)Bh;
    const char* pBl = (const char*)Bl;

    for (int ks = 0; ks < K / BK; ks++) {
        const int k0 = ks * BK;
        if (ks) __syncthreads();
#pragma unroll
        for (int r = 0; r < 4; r++) {
            size_t offA = ((size_t)(bm + srow[r]) * K + k0 + sslot[r] * 8) * 2;
            size_t offB = ((size_t)(bn + srow[r]) * K + k0 + sslot[r] * 8) * 2;
            int ldso = r * 4096 + wv * 1024;      // wave-uniform dest; HW adds lane*16
            gl_lds16(pAh + offA, (char*)sAh + ldso);
            gl_lds16(pAl + offA, (char*)sAl + ldso);
            gl_lds16(pBh + offB, (char*)sBh + ldso);
            gl_lds16(pBl + offB, (char*)sBl + ldso);
        }
        __syncthreads();

#pragma unroll
        for (int kk = 0; kk < 2; kk++) {
            bf16x8 ah[4], al[4], bh[4], bl[4];
#pragma unroll
            for (int f = 0; f < 4; f++) {
                int mr = wr * 64 + f * 16 + l15;
                int offa = mr * 128 + (((kk * 4 + kq) ^ (mr & 7)) * 16);
                ah[f] = *(const bf16x8*)((const char*)sAh + offa);
                al[f] = *(const bf16x8*)((const char*)sAl + offa);
                int nr = wc * 64 + f * 16 + l15;
                int offb = nr * 128 + (((kk * 4 + kq) ^ (nr & 7)) * 16);
                bh[f] = *(const bf16x8*)((const char*)sBh + offb);
                bl[f] = *(const bf16x8*)((const char*)sBl + offb);
            }
#pragma unroll
            for (int mf = 0; mf < 4; mf++)
#pragma unroll
                for (int nf = 0; nf < 4; nf++) {
                    acc[mf][nf] = __builtin_amdgcn_mfma_f32_16x16x32_bf16(ah[mf], bh[nf], acc[mf][nf], 0, 0, 0);
                    acc[mf][nf] = __builtin_amdgcn_mfma_f32_16x16x32_bf16(ah[mf], bl[nf], acc[mf][nf], 0, 0, 0);
                    acc[mf][nf] = __builtin_amdgcn_mfma_f32_16x16x32_bf16(al[mf], bh[nf], acc[mf][nf], 0, 0, 0);
                }
        }
    }

#pragma unroll
    for (int mf = 0; mf < 4; mf++) {
        const int r0 = bm + wr * 64 + mf * 16 + kq * 4;
#pragma unroll
        for (int nf = 0; nf < 4; nf++) {
            const int cc = bn + wc * 64 + nf * 16 + l15;
#pragma unroll
            for (int rr = 0; rr < 4; rr++)
                C[(size_t)(r0 + rr) * N + cc] = acc[mf][nf][rr];
        }
    }
}

// ---------------- launch ----------------
extern "C" void kernel_launch(void* const* d_in, const int* in_sizes, int n_in,
                              void* d_out, int out_size, void* d_ws, size_t ws_size,
                              hipStream_t stream)
{
    const float* U    = (const float*)d_in[0];
    const float* B    = (const float*)d_in[1];
    const float* rs_U = (const float*)d_in[2];
    const float* rs_B = (const float*)d_in[3];
    const float* cb_U = (const float*)d_in[4];
    const float* cb_B = (const float*)d_in[5];
    float* out = (float*)d_out;

    const int M = 32768, K = 256, N = 1024;

    ushort* Ahi  = (ushort*)d_ws;
    ushort* Alo  = Ahi + (size_t)M * K;
    ushort* BThi = Alo + (size_t)M * K;
    ushort* BTlo = BThi + (size_t)N * K;

    // U: 1,048,576 groups = 65,536 tiles of 16; 1024 blocks x 4 waves x 16 tiles
    pq_quant_mfma_u<<<1024, 256, 0, stream>>>(U, cb_U, rs_U, Ahi, Alo);
    pq_quant_split_T<<<128, 256, 0, stream>>>(B, cb_B, rs_B, BThi, BTlo, 7, K);

    gemm3<<<2048, 256, 0, stream>>>(Ahi, Alo, BThi, BTlo, out, M, N, K);
}